// Round 2
// baseline (527.524 us; speedup 1.0000x reference)
//
#include <hip/hip_runtime.h>
#include <math.h>

// ---------------------------------------------------------------------------
// AttentionNet weighted-anchor aggregator.
//   x:  (8, 448, 448, 3) f32
//   wp3:(8, 6, 4, 14, 14) f32   wp4:(8, 6, 4, 7, 7) f32   wp5:(8, 9, 4, 4, 4) f32
//   out:(32, 224, 224, 3) f32 = sum over 21 configs of
//        resize_bilinear( einsum('bkij,bihjwc->bkhwc', w, patches), 224,224 )
//
// Phase 0: init_tables  — normalized, zero-padded 4-tap bilinear weight tables
//                         (21 cfg x {H,W} x 224 x {w[4], i0}) at head of ws.
// Phase A: agg_kernel   — weighted patch aggregation into ws (float4/pixel).
// Phase B: resize_kernel— 16x16 output tiles, tables staged in LDS, fixed
//                         4x4 tap loop with float4 loads, accumulate into out.
// ---------------------------------------------------------------------------

#define BATCH 8
#define KK 4
#define OUT_HW 224
#define IMG_HW 448
#define NCFG 21

#define TBL_ENT 5                       // 4 weights + i0 (bitcast int)
#define TBL_PER_DIM (OUT_HW * TBL_ENT)  // 1120 floats
#define TBL_PER_CFG (2 * TBL_PER_DIM)   // 2240 floats
#define TBL_FLOATS (NCFG * TBL_PER_CFG) // 47040 floats
#define TBL_BYTES (TBL_FLOATS * 4)      // 188160 B (16B-divisible)

struct CfgEntry {
    int kh, kw;          // patch kernel size
    int stride;
    int p0, p1;          // padding
    int gh, gw;          // weight grid
    int layer;           // 0=p3, 1=p4, 2=p5
    int anchor;          // anchor index within layer
    int tbl;             // global cfg index (table lookup)
    int ws_off;          // float4 offset of this config's agg in agg region
    int block_start;     // first block of this config in agg_kernel grid
    int blocks_per_img;  // ceil(kh*kw/256)
};

struct GroupArgs {
    CfgEntry e[NCFG];
    int n;
};

struct TablesArgs {
    int kh[NCFG];
    int kw[NCFG];
};

// ---------------------------------------------------------------------------
// Phase 0: per (cfg, dim, out-coord) normalized 4-tap weights.
// jax.image.resize('bilinear', antialias=True):
//   inv = in/out; ks = max(inv,1); sf = (o+0.5)*inv - 0.5
//   w_i = max(0, 1 - |i-sf|/ks) for i in [ceil(sf-ks), floor(sf+ks)] clamped,
//   normalized by their sum. Tap count <= 4 for all 21 configs; zero-pad.
// ---------------------------------------------------------------------------
__global__ __launch_bounds__(256) void init_tables(float* __restrict__ tbl,
                                                   TablesArgs t) {
    int cfg = blockIdx.x >> 1;
    int dim = blockIdx.x & 1;   // 0=H, 1=W
    int o = threadIdx.x;
    if (o >= OUT_HW) return;
    int n = dim ? t.kw[cfg] : t.kh[cfg];

    float inv = (float)(1.0 / ((double)OUT_HW / (double)n));
    float ks  = inv > 1.f ? inv : 1.f;
    float rks = 1.f / ks;
    float sf  = ((float)o + 0.5f) * inv - 0.5f;
    int i0 = (int)ceilf(sf - ks);  if (i0 < 0) i0 = 0;
    int i1 = (int)floorf(sf + ks); if (i1 > n - 1) i1 = n - 1;
    float sum = 0.f;
    for (int i = i0; i <= i1; ++i) {
        float v = 1.f - fabsf((float)i - sf) * rks;
        sum += (v > 0.f ? v : 0.f);
    }
    float rsum = 1.f / sum;
    float* e = tbl + (size_t)cfg * TBL_PER_CFG + dim * TBL_PER_DIM + o * TBL_ENT;
#pragma unroll
    for (int d = 0; d < 4; ++d) {
        int i = i0 + d;
        float v = 0.f;
        if (i <= i1) {
            v = 1.f - fabsf((float)i - sf) * rks;
            v = (v > 0.f ? v : 0.f) * rsum;
        }
        e[d] = v;
    }
    e[4] = __int_as_float(i0);
}

// ---------------------------------------------------------------------------
// Phase A: agg[bk, h, w] (float4: c0,c1,c2,0) =
//   sum_{i,j} W[b,k,i,j] * X[b, i*s+h-p0, j*s+w-p1, c]  (zero outside image)
// One thread per (b, h, w), all 4 k and 3 c.
// ---------------------------------------------------------------------------
__global__ __launch_bounds__(256) void agg_kernel(
        const float* __restrict__ x,
        const float* __restrict__ wp3,
        const float* __restrict__ wp4,
        const float* __restrict__ wp5,
        float4* __restrict__ agg,
        GroupArgs g) {
    int bid = blockIdx.x;
    int ci = 0;
    while (ci + 1 < g.n && bid >= g.e[ci + 1].block_start) ci++;
    const CfgEntry c = g.e[ci];

    int local = bid - c.block_start;
    int b     = local / c.blocks_per_img;
    int sblk  = local - b * c.blocks_per_img;
    int gsz   = c.gh * c.gw;

    const float* wsrc;
    if (c.layer == 0)      wsrc = wp3 + (size_t)(b * 6 + c.anchor) * (KK * 14 * 14);
    else if (c.layer == 1) wsrc = wp4 + (size_t)(b * 6 + c.anchor) * (KK * 7 * 7);
    else                   wsrc = wp5 + (size_t)(b * 9 + c.anchor) * (KK * 4 * 4);

    __shared__ float lw[KK * 14 * 14];   // max 784 floats
    for (int t = threadIdx.x; t < KK * gsz; t += blockDim.x) lw[t] = wsrc[t];
    __syncthreads();

    int npix = c.kh * c.kw;
    int idx  = sblk * 256 + threadIdx.x;
    if (idx >= npix) return;

    int h = idx / c.kw;
    int w = idx - h * c.kw;

    float acc[KK][3];
#pragma unroll
    for (int k = 0; k < KK; ++k) { acc[k][0] = 0.f; acc[k][1] = 0.f; acc[k][2] = 0.f; }

    int rowb = h - c.p0;
    int colb = w - c.p1;
    for (int i = 0; i < c.gh; ++i) {
        int row = rowb + i * c.stride;
        if ((unsigned)row >= (unsigned)IMG_HW) continue;
        const float* xrow = x + ((size_t)b * IMG_HW + row) * (IMG_HW * 3);
        for (int j = 0; j < c.gw; ++j) {
            int col = colb + j * c.stride;
            if ((unsigned)col >= (unsigned)IMG_HW) continue;
            const float* xp = xrow + col * 3;
            float x0 = xp[0], x1 = xp[1], x2 = xp[2];
            int wi = i * c.gw + j;
#pragma unroll
            for (int k = 0; k < KK; ++k) {
                float wv = lw[k * gsz + wi];
                acc[k][0] = fmaf(wv, x0, acc[k][0]);
                acc[k][1] = fmaf(wv, x1, acc[k][1]);
                acc[k][2] = fmaf(wv, x2, acc[k][2]);
            }
        }
    }

#pragma unroll
    for (int k = 0; k < KK; ++k) {
        agg[(size_t)c.ws_off + (size_t)(b * KK + k) * npix + idx] =
            make_float4(acc[k][0], acc[k][1], acc[k][2], 0.f);
    }
}

// ---------------------------------------------------------------------------
// Phase B: out[bk,y,x,c] (+)= sum_cfg sum_{4x4 taps} Hw[d]*Ww[e]*agg[...]
// Block = 16x16 output tile for one bk; all group configs' table entries for
// this tile staged in LDS once.
// ---------------------------------------------------------------------------
__global__ __launch_bounds__(256) void resize_kernel(
        const float4* __restrict__ agg,
        const float* __restrict__ tbl,
        float* __restrict__ out,
        GroupArgs g, int accumulate) {
    const int tx = threadIdx.x & 15;
    const int ty = threadIdx.x >> 4;
    const int xo = blockIdx.x * 16 + tx;
    const int yo = blockIdx.y * 16 + ty;
    const int bk = blockIdx.z;

    __shared__ float lds[NCFG * 160];   // per cfg: 16 H entries + 16 W entries

    const int nent = g.n * 32;
    for (int e = threadIdx.x; e < nent; e += 256) {
        int ci  = e >> 5;
        int r   = e & 31;
        int isW = r >> 4;
        int idx = r & 15;
        int base_o = isW ? (blockIdx.x * 16) : (blockIdx.y * 16);
        const float* src = tbl + (size_t)g.e[ci].tbl * TBL_PER_CFG
                               + isW * TBL_PER_DIM + (base_o + idx) * TBL_ENT;
        float* dst = lds + ci * 160 + isW * 80 + idx * TBL_ENT;
#pragma unroll
        for (int q = 0; q < TBL_ENT; ++q) dst[q] = src[q];
    }
    __syncthreads();

    size_t obase = (((size_t)bk * OUT_HW + yo) * OUT_HW + xo) * 3;
    float a0, a1, a2;
    if (accumulate) { a0 = out[obase]; a1 = out[obase + 1]; a2 = out[obase + 2]; }
    else            { a0 = 0.f; a1 = 0.f; a2 = 0.f; }

    for (int ci = 0; ci < g.n; ++ci) {
        const int kh = g.e[ci].kh;
        const int kw = g.e[ci].kw;

        const float* H = lds + ci * 160 + ty * TBL_ENT;
        const float* W = lds + ci * 160 + 80 + tx * TBL_ENT;
        float wh0 = H[0], wh1 = H[1], wh2 = H[2], wh3 = H[3];
        int   i0  = __float_as_int(H[4]);
        float ww0 = W[0], ww1 = W[1], ww2 = W[2], ww3 = W[3];
        int   j0  = __float_as_int(W[4]);

        const float4* base = agg + (size_t)g.e[ci].ws_off + (size_t)bk * kh * kw;
        int jc0 = j0;
        int jc1 = j0 + 1 < kw ? j0 + 1 : kw - 1;
        int jc2 = j0 + 2 < kw ? j0 + 2 : kw - 1;
        int jc3 = j0 + 3 < kw ? j0 + 3 : kw - 1;
        float wh[4] = {wh0, wh1, wh2, wh3};
#pragma unroll
        for (int d = 0; d < 4; ++d) {
            int i = i0 + d < kh ? i0 + d : kh - 1;
            const float4* rp = base + (size_t)i * kw;
            float4 v0 = rp[jc0];
            float4 v1 = rp[jc1];
            float4 v2 = rp[jc2];
            float4 v3 = rp[jc3];
            float r0 = fmaf(ww3, v3.x, fmaf(ww2, v2.x, fmaf(ww1, v1.x, ww0 * v0.x)));
            float r1 = fmaf(ww3, v3.y, fmaf(ww2, v2.y, fmaf(ww1, v1.y, ww0 * v0.y)));
            float r2 = fmaf(ww3, v3.z, fmaf(ww2, v2.z, fmaf(ww1, v1.z, ww0 * v0.z)));
            a0 = fmaf(wh[d], r0, a0);
            a1 = fmaf(wh[d], r1, a1);
            a2 = fmaf(wh[d], r2, a2);
        }
    }

    out[obase + 0] = a0;
    out[obase + 1] = a1;
    out[obase + 2] = a2;
}

// ---------------------------------------------------------------------------
// Host launch
// ---------------------------------------------------------------------------
extern "C" void kernel_launch(void* const* d_in, const int* in_sizes, int n_in,
                              void* d_out, int out_size, void* d_ws, size_t ws_size,
                              hipStream_t stream) {
    const float* x   = (const float*)d_in[0];
    const float* wp3 = (const float*)d_in[1];
    const float* wp4 = (const float*)d_in[2];
    const float* wp5 = (const float*)d_in[3];
    float* out = (float*)d_out;
    float* tbl = (float*)d_ws;
    float4* agg = (float4*)((char*)d_ws + TBL_BYTES);

    // Build the 21 configs exactly as the reference does (double precision).
    struct { int stride, size, nscale; double scales[3]; int gh; } layers[3] = {
        {32, 48, 2, {pow(2.0, 1.0 / 3.0), pow(2.0, 2.0 / 3.0), 0.0}, 14},
        {64, 96, 2, {pow(2.0, 1.0 / 3.0), pow(2.0, 2.0 / 3.0), 0.0}, 7},
        {128, 192, 3, {1.0, pow(2.0, 1.0 / 3.0), pow(2.0, 2.0 / 3.0)}, 4},
    };
    const double ars[3] = {0.667, 1.0, 1.5};

    CfgEntry cfg[NCFG];
    TablesArgs ta;
    int nc = 0;
    for (int L = 0; L < 3; ++L) {
        int anchor = 0;
        for (int si = 0; si < layers[L].nscale; ++si) {
            for (int ai = 0; ai < 3; ++ai) {
                double ss = (double)layers[L].size * layers[L].scales[si];
                double sq = pow(ars[ai], 0.5);
                int kh = (int)(ss / sq);
                int kw = (int)(ss * sq);
                CfgEntry& e = cfg[nc];
                e.kh = kh; e.kw = kw;
                e.stride = layers[L].stride;
                e.p0 = (int)ceil((double)(kh - layers[L].stride) / 2.0);
                e.p1 = (int)ceil((double)(kw - layers[L].stride) / 2.0);
                e.gh = layers[L].gh; e.gw = layers[L].gh;
                e.layer = L; e.anchor = anchor++;
                e.tbl = nc;
                e.ws_off = 0; e.block_start = 0;
                e.blocks_per_img = (kh * kw + 255) / 256;
                ta.kh[nc] = kh; ta.kw[nc] = kw;
                ++nc;
            }
        }
    }

    init_tables<<<NCFG * 2, 256, 0, stream>>>(tbl, ta);

    // Greedy grouping by agg-region capacity (cap 128 MB for L3 locality).
    size_t avail = ws_size - TBL_BYTES;
    size_t cap_bytes = avail < (size_t)(128u * 1024u * 1024u) ? avail
                                                              : (size_t)(128u * 1024u * 1024u);
    size_t cap_f4 = cap_bytes / 16;

    const int out_total  = BATCH * KK * OUT_HW * OUT_HW;  // 1.6M pixels
    dim3 rgrid(OUT_HW / 16, OUT_HW / 16, BATCH * KK);

    int i = 0;
    int first = 1;
    while (i < NCFG) {
        GroupArgs g;
        g.n = 0;
        size_t used = 0;
        int blocks = 0;
        while (i < NCFG) {
            size_t need = (size_t)cfg[i].kh * cfg[i].kw * (BATCH * KK); // float4s
            if (g.n > 0 && used + need > cap_f4) break;
            CfgEntry e = cfg[i];
            e.ws_off = (int)used;
            e.block_start = blocks;
            blocks += e.blocks_per_img * BATCH;
            used += need;
            g.e[g.n++] = e;
            ++i;
            if (used >= cap_f4) break;
        }
        agg_kernel<<<blocks, 256, 0, stream>>>(x, wp3, wp4, wp5, agg, g);
        resize_kernel<<<rgrid, 256, 0, stream>>>(agg, tbl, out, g, first ? 0 : 1);
        first = 0;
    }
    (void)out_total; (void)in_sizes; (void)n_in; (void)out_size;
}

// Round 3
// 347.338 us; speedup vs baseline: 1.5188x; 1.5188x over previous
//
#include <hip/hip_runtime.h>
#include <math.h>

// ---------------------------------------------------------------------------
// AttentionNet weighted-anchor aggregator.
//   x:  (8, 448, 448, 3) f32
//   wp3:(8, 6, 4, 14, 14) f32   wp4:(8, 6, 4, 7, 7) f32   wp5:(8, 9, 4, 4, 4) f32
//   out:(32, 224, 224, 3) f32 = sum over 21 configs of
//        resize_bilinear( einsum('bkij,bihjwc->bkhwc', w, patches), 224,224 )
//
// Phase 0: init_tables — normalized zero-padded 4-tap weights (float4) + i0
//                        (int) per (cfg, dim, out-coord), at head of ws.
// Phase A: agg_kernel  — weighted patch aggregation, bf16x4 (8 B/px) into ws.
// Phase B: resize_kernel — per 16x16 out tile per cfg: stage the needed agg
//          window into LDS (coalesced), then tap-exact taps<TH,TW> from LDS.
// ---------------------------------------------------------------------------

#define BATCH 8
#define KK 4
#define OUT_HW 224
#define IMG_HW 448
#define NCFG 21

#define WTBL_F4   (NCFG * 2 * OUT_HW)          // float4 weight entries
#define WTBL_BYTES (WTBL_F4 * 16)              // 150528
#define ITBL_BYTES (NCFG * 2 * OUT_HW * 4)     // 37632
#define TBL_BYTES (WTBL_BYTES + ITBL_BYTES)    // 188160 (16B aligned)

#define REGION_PX 768                          // max needed window is 580 px

struct CfgEntry {
    int kh, kw;          // patch kernel size
    int stride;
    int p0, p1;          // padding
    int gh, gw;          // weight grid
    int layer;           // 0=p3, 1=p4, 2=p5
    int anchor;          // anchor index within layer
    int tbl;             // global cfg index (table lookup)
    int mth, mtw;        // max tap count per dim (2..4)
    int ws_off;          // px (uint2) offset of this config's agg in agg region
    int block_start;     // first block of this config in agg_kernel grid
    int blocks_per_img;  // ceil(kh*kw/256)
};

struct GroupArgs {
    CfgEntry e[NCFG];
    int n;
};

struct TablesArgs {
    int kh[NCFG];
    int kw[NCFG];
};

// ---------------------------------------------------------------------------
// bf16 helpers
// ---------------------------------------------------------------------------
__device__ inline unsigned int bf16_rne(float f) {
    unsigned int u = __float_as_uint(f);
    return (u + 0x7fffu + ((u >> 16) & 1u)) >> 16;
}

// ---------------------------------------------------------------------------
// Phase 0: per (cfg, dim, out-coord) normalized taps.
// jax.image.resize('bilinear', antialias=True):
//   inv = in/out; ks = max(inv,1); sf = (o+0.5)*inv - 0.5
//   taps i in [ceil(sf-ks), floor(sf+ks)] clamped to [0,in), weights
//   max(0, 1-|i-sf|/ks) normalized by their sum. Tap count <= 4 here.
// ---------------------------------------------------------------------------
__global__ __launch_bounds__(256) void init_tables(float4* __restrict__ wtbl,
                                                   int* __restrict__ itbl,
                                                   TablesArgs t) {
    int cfg = blockIdx.x >> 1;
    int dim = blockIdx.x & 1;   // 0=H, 1=W
    int o = threadIdx.x;
    if (o >= OUT_HW) return;
    int n = dim ? t.kw[cfg] : t.kh[cfg];

    float inv = (float)(1.0 / ((double)OUT_HW / (double)n));
    float ks  = inv > 1.f ? inv : 1.f;
    float rks = 1.f / ks;
    float sf  = ((float)o + 0.5f) * inv - 0.5f;
    int i0 = (int)ceilf(sf - ks);  if (i0 < 0) i0 = 0;
    int i1 = (int)floorf(sf + ks); if (i1 > n - 1) i1 = n - 1;
    float sum = 0.f;
    for (int i = i0; i <= i1; ++i) {
        float v = 1.f - fabsf((float)i - sf) * rks;
        sum += (v > 0.f ? v : 0.f);
    }
    float rsum = 1.f / sum;
    float w[4];
#pragma unroll
    for (int d = 0; d < 4; ++d) {
        int i = i0 + d;
        float v = 0.f;
        if (i <= i1) {
            v = 1.f - fabsf((float)i - sf) * rks;
            v = (v > 0.f ? v : 0.f) * rsum;
        }
        w[d] = v;
    }
    int idx = cfg * (2 * OUT_HW) + dim * OUT_HW + o;
    wtbl[idx] = make_float4(w[0], w[1], w[2], w[3]);
    itbl[idx] = i0;
}

// ---------------------------------------------------------------------------
// Phase A: agg[bk, h, w] (bf16x4 in uint2) =
//   sum_{i,j} W[b,k,i,j] * X[b, i*s+h-p0, j*s+w-p1, :]  (zero outside image)
// One thread per (b, h, w), all 4 k and 3 c.
// ---------------------------------------------------------------------------
struct F3 { float a, b, c; };   // align 4, loads merge to dwordx3

__global__ __launch_bounds__(256) void agg_kernel(
        const float* __restrict__ x,
        const float* __restrict__ wp3,
        const float* __restrict__ wp4,
        const float* __restrict__ wp5,
        uint2* __restrict__ agg,
        GroupArgs g) {
    int bid = blockIdx.x;
    int ci = 0;
    while (ci + 1 < g.n && bid >= g.e[ci + 1].block_start) ci++;
    const CfgEntry c = g.e[ci];

    int local = bid - c.block_start;
    int b     = local / c.blocks_per_img;
    int sblk  = local - b * c.blocks_per_img;
    int gsz   = c.gh * c.gw;

    const float* wsrc;
    if (c.layer == 0)      wsrc = wp3 + (size_t)(b * 6 + c.anchor) * (KK * 14 * 14);
    else if (c.layer == 1) wsrc = wp4 + (size_t)(b * 6 + c.anchor) * (KK * 7 * 7);
    else                   wsrc = wp5 + (size_t)(b * 9 + c.anchor) * (KK * 4 * 4);

    __shared__ float lw[KK * 14 * 14];   // max 784 floats
    for (int t = threadIdx.x; t < KK * gsz; t += blockDim.x) lw[t] = wsrc[t];
    __syncthreads();

    int npix = c.kh * c.kw;
    int idx  = sblk * 256 + threadIdx.x;
    if (idx >= npix) return;

    int h = idx / c.kw;
    int w = idx - h * c.kw;

    float acc[KK][3];
#pragma unroll
    for (int k = 0; k < KK; ++k) { acc[k][0] = 0.f; acc[k][1] = 0.f; acc[k][2] = 0.f; }

    int rowb = h - c.p0;
    int colb = w - c.p1;
    for (int i = 0; i < c.gh; ++i) {
        int row = rowb + i * c.stride;
        if ((unsigned)row >= (unsigned)IMG_HW) continue;
        const float* xrow = x + ((size_t)b * IMG_HW + row) * (IMG_HW * 3);
        for (int j = 0; j < c.gw; ++j) {
            int col = colb + j * c.stride;
            if ((unsigned)col >= (unsigned)IMG_HW) continue;
            F3 xv = *(const F3*)(xrow + col * 3);
            int wi = i * c.gw + j;
#pragma unroll
            for (int k = 0; k < KK; ++k) {
                float wv = lw[k * gsz + wi];
                acc[k][0] = fmaf(wv, xv.a, acc[k][0]);
                acc[k][1] = fmaf(wv, xv.b, acc[k][1]);
                acc[k][2] = fmaf(wv, xv.c, acc[k][2]);
            }
        }
    }

#pragma unroll
    for (int k = 0; k < KK; ++k) {
        uint2 o;
        o.x = bf16_rne(acc[k][0]) | (bf16_rne(acc[k][1]) << 16);
        o.y = bf16_rne(acc[k][2]);
        agg[(size_t)c.ws_off + (size_t)(b * KK + k) * npix + idx] = o;
    }
}

// ---------------------------------------------------------------------------
// Tap micro-kernel: TH x TW taps from the LDS region.
// ---------------------------------------------------------------------------
template <int TH, int TW>
__device__ inline void taps(const uint2* __restrict__ rp0, int rcols,
                            float4 wh4, float4 ww4,
                            float& a0, float& a1, float& a2) {
    const float* wh = (const float*)&wh4;
    const float* ww = (const float*)&ww4;
#pragma unroll
    for (int d = 0; d < TH; ++d) {
        const uint2* rp = rp0 + d * rcols;
        float r0 = 0.f, r1 = 0.f, r2 = 0.f;
#pragma unroll
        for (int e = 0; e < TW; ++e) {
            uint2 v = rp[e];
            float c0 = __uint_as_float(v.x << 16);
            float c1 = __uint_as_float(v.x & 0xffff0000u);
            float c2 = __uint_as_float(v.y << 16);
            float w = ww[e];
            r0 = fmaf(w, c0, r0);
            r1 = fmaf(w, c1, r1);
            r2 = fmaf(w, c2, r2);
        }
        a0 = fmaf(wh[d], r0, a0);
        a1 = fmaf(wh[d], r1, a1);
        a2 = fmaf(wh[d], r2, a2);
    }
}

// ---------------------------------------------------------------------------
// Phase B: block = 16x16 output tile for one bk. Per cfg: stage the agg
// window for this tile into LDS (coalesced uint2), then tap from LDS.
// ---------------------------------------------------------------------------
__global__ __launch_bounds__(256) void resize_kernel(
        const uint2* __restrict__ agg,
        const float4* __restrict__ wtbl,
        const int* __restrict__ itbl,
        float* __restrict__ out,
        GroupArgs g, int accumulate) {
    const int tid = threadIdx.x;
    const int tx = tid & 15;
    const int ty = tid >> 4;
    const int xo = blockIdx.x * 16 + tx;
    const int yo = blockIdx.y * 16 + ty;
    const int bk = blockIdx.z;

    __shared__ float4 wlds[NCFG * 32];   // per cfg: 16 H entries + 16 W entries
    __shared__ int    ilds[NCFG * 32];
    __shared__ uint2  region[REGION_PX];

    const int nent = g.n * 32;
    for (int e = tid; e < nent; e += 256) {
        int ci  = e >> 5;
        int r   = e & 31;
        int isW = r >> 4;
        int idx = r & 15;
        int base_o = isW ? (blockIdx.x * 16) : (blockIdx.y * 16);
        int src = g.e[ci].tbl * (2 * OUT_HW) + isW * OUT_HW + base_o + idx;
        wlds[ci * 32 + r] = wtbl[src];
        ilds[ci * 32 + r] = itbl[src];
    }
    __syncthreads();

    size_t obase = (((size_t)bk * OUT_HW + yo) * OUT_HW + xo) * 3;
    float a0, a1, a2;
    if (accumulate) { a0 = out[obase]; a1 = out[obase + 1]; a2 = out[obase + 2]; }
    else            { a0 = 0.f; a1 = 0.f; a2 = 0.f; }

    for (int ci = 0; ci < g.n; ++ci) {
        const int kh  = g.e[ci].kh;
        const int kw  = g.e[ci].kw;
        const int mth = g.e[ci].mth;
        const int mtw = g.e[ci].mtw;

        // tile window bounds (wave-uniform: entries 0/15 only)
        int ri0 = ilds[ci * 32 + 0];
        int ri1 = ilds[ci * 32 + 15] + mth - 1;
        int ci0 = ilds[ci * 32 + 16];
        int ci1 = ilds[ci * 32 + 31] + mtw - 1;
        int rrows = ri1 - ri0 + 1;
        int rcols = ci1 - ci0 + 1;

        const uint2* base = agg + (size_t)g.e[ci].ws_off + (size_t)bk * kh * kw;

        __syncthreads();   // previous cfg's taps done before overwrite
        {
            int cc = tid & 31;
            int gj = ci0 + cc;
            if (gj > kw - 1) gj = kw - 1;
            bool cok = cc < rcols;
            for (int r = tid >> 5; r < rrows; r += 8) {
                int gi = ri0 + r;
                if (gi > kh - 1) gi = kh - 1;
                if (cok) region[r * rcols + cc] = base[gi * kw + gj];
            }
        }
        __syncthreads();

        float4 wh4 = wlds[ci * 32 + ty];
        float4 ww4 = wlds[ci * 32 + 16 + tx];
        int i0 = ilds[ci * 32 + ty];
        int j0 = ilds[ci * 32 + 16 + tx];
        const uint2* rp0 = region + (i0 - ri0) * rcols + (j0 - ci0);

        switch ((mth << 2) | mtw) {
            case (2 << 2) | 2: taps<2, 2>(rp0, rcols, wh4, ww4, a0, a1, a2); break;
            case (3 << 2) | 2: taps<3, 2>(rp0, rcols, wh4, ww4, a0, a1, a2); break;
            case (2 << 2) | 3: taps<2, 3>(rp0, rcols, wh4, ww4, a0, a1, a2); break;
            case (3 << 2) | 3: taps<3, 3>(rp0, rcols, wh4, ww4, a0, a1, a2); break;
            case (4 << 2) | 3: taps<4, 3>(rp0, rcols, wh4, ww4, a0, a1, a2); break;
            case (3 << 2) | 4: taps<3, 4>(rp0, rcols, wh4, ww4, a0, a1, a2); break;
            default:           taps<4, 4>(rp0, rcols, wh4, ww4, a0, a1, a2); break;
        }
    }

    out[obase + 0] = a0;
    out[obase + 1] = a1;
    out[obase + 2] = a2;
}

// ---------------------------------------------------------------------------
// Host launch
// ---------------------------------------------------------------------------
extern "C" void kernel_launch(void* const* d_in, const int* in_sizes, int n_in,
                              void* d_out, int out_size, void* d_ws, size_t ws_size,
                              hipStream_t stream) {
    const float* x   = (const float*)d_in[0];
    const float* wp3 = (const float*)d_in[1];
    const float* wp4 = (const float*)d_in[2];
    const float* wp5 = (const float*)d_in[3];
    float* out = (float*)d_out;
    float4* wtbl = (float4*)d_ws;
    int*    itbl = (int*)((char*)d_ws + WTBL_BYTES);
    uint2*  agg  = (uint2*)((char*)d_ws + TBL_BYTES);

    // Build the 21 configs exactly as the reference does (double precision).
    struct { int stride, size, nscale; double scales[3]; int gh; } layers[3] = {
        {32, 48, 2, {pow(2.0, 1.0 / 3.0), pow(2.0, 2.0 / 3.0), 0.0}, 14},
        {64, 96, 2, {pow(2.0, 1.0 / 3.0), pow(2.0, 2.0 / 3.0), 0.0}, 7},
        {128, 192, 3, {1.0, pow(2.0, 1.0 / 3.0), pow(2.0, 2.0 / 3.0)}, 4},
    };
    const double ars[3] = {0.667, 1.0, 1.5};

    CfgEntry cfg[NCFG];
    TablesArgs ta;
    int nc = 0;
    for (int L = 0; L < 3; ++L) {
        int anchor = 0;
        for (int si = 0; si < layers[L].nscale; ++si) {
            for (int ai = 0; ai < 3; ++ai) {
                double ss = (double)layers[L].size * layers[L].scales[si];
                double sq = pow(ars[ai], 0.5);
                int kh = (int)(ss / sq);
                int kw = (int)(ss * sq);
                CfgEntry& e = cfg[nc];
                e.kh = kh; e.kw = kw;
                e.stride = layers[L].stride;
                e.p0 = (int)ceil((double)(kh - layers[L].stride) / 2.0);
                e.p1 = (int)ceil((double)(kw - layers[L].stride) / 2.0);
                e.gh = layers[L].gh; e.gw = layers[L].gh;
                e.layer = L; e.anchor = anchor++;
                e.tbl = nc;
                // max tap count per dim: upscale => 2; downscale => floor(2in/out)+1
                e.mth = (kh < OUT_HW) ? 2 : (int)((2.0 * kh) / OUT_HW) + 1;
                e.mtw = (kw < OUT_HW) ? 2 : (int)((2.0 * kw) / OUT_HW) + 1;
                if (e.mth > 4) e.mth = 4;
                if (e.mtw > 4) e.mtw = 4;
                e.ws_off = 0; e.block_start = 0;
                e.blocks_per_img = (kh * kw + 255) / 256;
                ta.kh[nc] = kh; ta.kw[nc] = kw;
                ++nc;
            }
        }
    }

    init_tables<<<NCFG * 2, 256, 0, stream>>>(wtbl, itbl, ta);

    // Greedy grouping by agg-region capacity (use all available workspace).
    size_t cap_px = (ws_size - TBL_BYTES) / 8;   // uint2 px

    dim3 rgrid(OUT_HW / 16, OUT_HW / 16, BATCH * KK);

    int i = 0;
    int first = 1;
    while (i < NCFG) {
        GroupArgs g;
        g.n = 0;
        size_t used = 0;
        int blocks = 0;
        while (i < NCFG) {
            size_t need = (size_t)cfg[i].kh * cfg[i].kw * (BATCH * KK); // px
            if (g.n > 0 && used + need > cap_px) break;
            CfgEntry e = cfg[i];
            e.ws_off = (int)used;
            e.block_start = blocks;
            blocks += e.blocks_per_img * BATCH;
            used += need;
            g.e[g.n++] = e;
            ++i;
            if (used >= cap_px) break;
        }
        agg_kernel<<<blocks, 256, 0, stream>>>(x, wp3, wp4, wp5, agg, g);
        resize_kernel<<<rgrid, 256, 0, stream>>>(agg, wtbl, itbl, out, g, first ? 0 : 1);
        first = 0;
    }
    (void)in_sizes; (void)n_in; (void)out_size;
}